// Round 8
// baseline (378.147 us; speedup 1.0000x reference)
//
#include <hip/hip_runtime.h>

#define BB 32
#define TT 1024
#define NN 128
#define YB 256   // y steps buffered in LDS between flushes

// DPP adds — pure VALU cross-lane (no lgkm waits). ctrl must be literal.
#define ROR_ADD(p, ctrl)                                                      \
  p += __int_as_float(__builtin_amdgcn_update_dpp(                            \
      0, __float_as_int(p), ctrl, 0xF, 0xF, true));
// row_bcast15 (0x142): lane15 -> lanes16-31, lane47 -> lanes48-63.
#define BCAST15_ADD(p) ROR_ADD(p, 0x142)
// row_bcast31 (0x143): lane31 -> lanes32-63. After ror*4 + bcast15 + bcast31,
// lanes 48..63 hold the full 64-lane sum.
#define BCAST31_ADD(p) ROR_ADD(p, 0x143)

__global__ __launch_bounds__(256, 4)   // 4 waves/EU min -> VGPR cap 128
void bdh_seq_kernel(const float* __restrict__ x,
                    const float* __restrict__ w_init,
                    const float* __restrict__ alpha_p,
                    const float* __restrict__ eta_p,
                    const int*   __restrict__ mask,
                    float* __restrict__ out)
{
    const int tid  = threadIdx.x;
    const int bidx = blockIdx.x;           // 1024 blocks
    const int b      = bidx & 31;          // batch; %8 pins batch to one XCD L2
    const int i_base = (bidx >> 5) << 2;   // 4 rows per block
    const int wv     = tid >> 6;           // wave id 0..3 == local row
    const int lane   = tid & 63;
    const int i      = i_base + wv;        // this wave's W row
    const int j0     = lane << 1;          // 2 cols per lane

    __shared__ float ybuf[YB][4];

    const float alpha = alpha_p[0];
    const float eta   = eta_p[0];

    const float* xb = x + (size_t)b * TT * NN;
    const int*   mb = mask + b * TT;

    float* wout = out + ((size_t)b * NN + i) * NN + j0;
    float* yout = out + (size_t)BB * NN * NN + (size_t)b * TT * NN;

    float2 w = *reinterpret_cast<const float2*>(
        w_init + ((size_t)b * NN + i) * NN + j0);

    // Double-buffered 8-step groups; prefetch distance = one full iteration.
    float2 Xc[8], Xn[8];
    float  xic[8], xin[8];
    int    mc[8],  mn[8];
    float  p[16];

#define LOADG(X, XI, M, tbase)                                                \
  {                                                                           \
    const float* gp = xb + (size_t)(tbase) * NN;                              \
    _Pragma("unroll")                                                         \
    for (int k = 0; k < 8; ++k) {                                             \
      X[k]  = *reinterpret_cast<const float2*>(gp + k * NN + j0);             \
      XI[k] = gp[k * NN + i];                                                 \
    }                                                                         \
    *reinterpret_cast<int4*>(&M[0]) =                                         \
        *reinterpret_cast<const int4*>(mb + (tbase));                         \
    *reinterpret_cast<int4*>(&M[4]) =                                         \
        *reinterpret_cast<const int4*>(mb + (tbase) + 4);                     \
  }

// Dot (reads w) + masked Hebbian update. Reduce deferred to batched phase.
#define COMPG(X, XI, M, pbase)                                                \
  {                                                                           \
    _Pragma("unroll")                                                         \
    for (int k = 0; k < 8; ++k) {                                             \
      const float aa = M[k] ? alpha : 1.0f;                                   \
      const float ci = (M[k] ? eta : 0.0f) * XI[k];                           \
      p[(pbase) + k] = fmaf(w.y, X[k].y, w.x * X[k].x);                       \
      w.x = fmaf(aa, w.x, ci * X[k].x);                                       \
      w.y = fmaf(aa, w.y, ci * X[k].y);                                       \
    }                                                                         \
  }

    LOADG(Xc, xic, mc, 0);
    LOADG(Xn, xin, mn, 8);

#pragma unroll 1
    for (int t = 0; t < TT; t += 16) {
        COMPG(Xc, xic, mc, 0);
        if (t + 16 < TT) LOADG(Xc, xic, mc, t + 16);   // prefetch next-next
        COMPG(Xn, xin, mn, 8);
        if (t + 24 < TT) LOADG(Xn, xin, mn, t + 24);

        // 16 independent 64-lane reduces, stage-outer -> full DPP ILP.
#pragma unroll
        for (int k = 0; k < 16; ++k) { ROR_ADD(p[k], 0x121); }
#pragma unroll
        for (int k = 0; k < 16; ++k) { ROR_ADD(p[k], 0x122); }
#pragma unroll
        for (int k = 0; k < 16; ++k) { ROR_ADD(p[k], 0x124); }
#pragma unroll
        for (int k = 0; k < 16; ++k) { ROR_ADD(p[k], 0x128); }
#pragma unroll
        for (int k = 0; k < 16; ++k) { BCAST15_ADD(p[k]); }
#pragma unroll
        for (int k = 0; k < 16; ++k) { BCAST31_ADD(p[k]); }

        if (lane == 48) {
#pragma unroll
            for (int k = 0; k < 16; ++k)
                ybuf[(t + k) & (YB - 1)][wv] = p[k];
        }

        // Flush 256 buffered y steps (4x per kernel).
        if (((t + 16) & (YB - 1)) == 0) {
            __syncthreads();
            const int t0 = t + 16 - YB;
#pragma unroll
            for (int pass = 0; pass < 4; ++pass) {
                const int idx = (pass << 8) + tid;
                const int tq  = idx >> 2;
                const int il  = idx & 3;
                yout[(size_t)(t0 + tq) * NN + i_base + il] = ybuf[tq][il];
            }
            __syncthreads();
        }
    }
#undef LOADG
#undef COMPG

    *reinterpret_cast<float2*>(wout) = w;
}

extern "C" void kernel_launch(void* const* d_in, const int* in_sizes, int n_in,
                              void* d_out, int out_size, void* d_ws, size_t ws_size,
                              hipStream_t stream)
{
    const float* x      = (const float*)d_in[0];
    const float* w_init = (const float*)d_in[1];
    const float* alpha  = (const float*)d_in[2];
    const float* eta    = (const float*)d_in[3];
    const int*   mask   = (const int*)d_in[4];
    float*       out    = (float*)d_out;

    dim3 grid(1024), block(256);
    hipLaunchKernelGGL(bdh_seq_kernel, grid, block, 0, stream,
                       x, w_init, alpha, eta, mask, out);
}

// Round 9
// 252.386 us; speedup vs baseline: 1.4983x; 1.4983x over previous
//
#include <hip/hip_runtime.h>

#define BB 32
#define TT 1024
#define NN 128
#define YB 256   // y steps buffered in LDS between flushes

// DPP adds — pure VALU cross-lane (no lgkm waits). ctrl must be literal.
#define ROR_ADD(p, ctrl)                                                      \
  p += __int_as_float(__builtin_amdgcn_update_dpp(                            \
      0, __float_as_int(p), ctrl, 0xF, 0xF, true));
// row_bcast15 (0x142): lane15 -> lanes16-31, lane47 -> lanes48-63.
#define BCAST15_ADD(p) ROR_ADD(p, 0x142)
// row_bcast31 (0x143): lane31 -> lanes32-63. After ror*4 + bcast15 + bcast31,
// lanes 48..63 hold the full 64-lane sum.
#define BCAST31_ADD(p) ROR_ADD(p, 0x143)

// NOTE: no min-waves arg. (256,4) made the backend cap VGPR at 64 and spill
// the whole pipeline state to scratch (WRITE_SIZE 18->58 MB, dur 378us).
__global__ __launch_bounds__(256)
void bdh_seq_kernel(const float* __restrict__ x,
                    const float* __restrict__ w_init,
                    const float* __restrict__ alpha_p,
                    const float* __restrict__ eta_p,
                    const int*   __restrict__ mask,
                    float* __restrict__ out)
{
    const int tid  = threadIdx.x;
    const int bidx = blockIdx.x;           // 1024 blocks
    const int b      = bidx & 31;          // batch; %8 pins batch to one XCD L2
    const int i_base = (bidx >> 5) << 2;   // 4 rows per block
    const int wv     = tid >> 6;           // wave id 0..3 == local row
    const int lane   = tid & 63;
    const int i      = i_base + wv;        // this wave's W row
    const int j0     = lane << 1;          // 2 cols per lane

    __shared__ float ybuf[YB][4];

    const float alpha = alpha_p[0];
    const float eta   = eta_p[0];

    const float* xb = x + (size_t)b * TT * NN;
    const int*   mb = mask + b * TT;

    float* wout = out + ((size_t)b * NN + i) * NN + j0;
    float* yout = out + (size_t)BB * NN * NN + (size_t)b * TT * NN;

    float2 w = *reinterpret_cast<const float2*>(
        w_init + ((size_t)b * NN + i) * NN + j0);

    // Double-buffered 8-step groups; prefetch distance = one full iteration.
    float2 Xc[8], Xn[8];
    float  xic[8], xin[8];
    int    mc[8],  mn[8];
    float  p[16];

#define LOADG(X, XI, M, tbase)                                                \
  {                                                                           \
    const float* gp = xb + (size_t)(tbase) * NN;                              \
    _Pragma("unroll")                                                         \
    for (int k = 0; k < 8; ++k) {                                             \
      X[k]  = *reinterpret_cast<const float2*>(gp + k * NN + j0);             \
      XI[k] = gp[k * NN + i];                                                 \
    }                                                                         \
    *reinterpret_cast<int4*>(&M[0]) =                                         \
        *reinterpret_cast<const int4*>(mb + (tbase));                         \
    *reinterpret_cast<int4*>(&M[4]) =                                         \
        *reinterpret_cast<const int4*>(mb + (tbase) + 4);                     \
  }

// Dot (reads w) + masked Hebbian update. Reduce deferred to batched phase.
#define COMPG(X, XI, M, pbase)                                                \
  {                                                                           \
    _Pragma("unroll")                                                         \
    for (int k = 0; k < 8; ++k) {                                             \
      const float aa = M[k] ? alpha : 1.0f;                                   \
      const float ci = (M[k] ? eta : 0.0f) * XI[k];                           \
      p[(pbase) + k] = fmaf(w.y, X[k].y, w.x * X[k].x);                       \
      w.x = fmaf(aa, w.x, ci * X[k].x);                                       \
      w.y = fmaf(aa, w.y, ci * X[k].y);                                       \
    }                                                                         \
  }

    LOADG(Xc, xic, mc, 0);
    LOADG(Xn, xin, mn, 8);

#pragma unroll 1
    for (int t = 0; t < TT; t += 16) {
        COMPG(Xc, xic, mc, 0);
        if (t + 16 < TT) LOADG(Xc, xic, mc, t + 16);   // prefetch next-next
        COMPG(Xn, xin, mn, 8);
        if (t + 24 < TT) LOADG(Xn, xin, mn, t + 24);

        // 16 independent 64-lane reduces, stage-outer -> full DPP ILP.
#pragma unroll
        for (int k = 0; k < 16; ++k) { ROR_ADD(p[k], 0x121); }
#pragma unroll
        for (int k = 0; k < 16; ++k) { ROR_ADD(p[k], 0x122); }
#pragma unroll
        for (int k = 0; k < 16; ++k) { ROR_ADD(p[k], 0x124); }
#pragma unroll
        for (int k = 0; k < 16; ++k) { ROR_ADD(p[k], 0x128); }
#pragma unroll
        for (int k = 0; k < 16; ++k) { BCAST15_ADD(p[k]); }
#pragma unroll
        for (int k = 0; k < 16; ++k) { BCAST31_ADD(p[k]); }

        if (lane == 48) {
#pragma unroll
            for (int k = 0; k < 16; ++k)
                ybuf[(t + k) & (YB - 1)][wv] = p[k];
        }

        // Flush 256 buffered y steps (4x per kernel).
        if (((t + 16) & (YB - 1)) == 0) {
            __syncthreads();
            const int t0 = t + 16 - YB;
#pragma unroll
            for (int pass = 0; pass < 4; ++pass) {
                const int idx = (pass << 8) + tid;
                const int tq  = idx >> 2;
                const int il  = idx & 3;
                yout[(size_t)(t0 + tq) * NN + i_base + il] = ybuf[tq][il];
            }
            __syncthreads();
        }
    }
#undef LOADG
#undef COMPG

    *reinterpret_cast<float2*>(wout) = w;
}

extern "C" void kernel_launch(void* const* d_in, const int* in_sizes, int n_in,
                              void* d_out, int out_size, void* d_ws, size_t ws_size,
                              hipStream_t stream)
{
    const float* x      = (const float*)d_in[0];
    const float* w_init = (const float*)d_in[1];
    const float* alpha  = (const float*)d_in[2];
    const float* eta    = (const float*)d_in[3];
    const int*   mask   = (const int*)d_in[4];
    float*       out    = (float*)d_out;

    dim3 grid(1024), block(256);
    hipLaunchKernelGGL(bdh_seq_kernel, grid, block, 0, stream,
                       x, w_init, alpha, eta, mask, out);
}

// Round 11
// 207.065 us; speedup vs baseline: 1.8262x; 1.2189x over previous
//
#include <hip/hip_runtime.h>

#define BB 32
#define TT 1024
#define NN 128
#define YB 256   // y steps buffered in LDS between flushes

// DPP row_ror:N add — pure-VALU 16-lane rotation reduce (ctrl must be literal).
// After ror 1,2,4,8 every lane of each 16-lane group holds the full 16-sum.
#define ROR_ADD(p, ctrl)                                                      \
  p += __int_as_float(__builtin_amdgcn_update_dpp(                            \
      0, __float_as_int(p), ctrl, 0xF, 0xF, true));

// C=8 layout: 16 lanes/row, 8 cols/lane, 4 rows/wave, 2 waves/block.
// 512 blocks -> 1024 waves = 1 wave/SIMD, 2 blocks/CU. Latency survived via
// W=A*V factoring (per-step coef = 1 mul, update = 1 FMA/elem) + precomputed
// per-step tables in LDS + 8-step-deep register prefetch.
__global__ __launch_bounds__(128)
void bdh_seq_kernel(const float* __restrict__ x,
                    const float* __restrict__ w_init,
                    const float* __restrict__ alpha_p,
                    const float* __restrict__ eta_p,
                    const int*   __restrict__ mask,
                    float* __restrict__ out)
{
    const int tid  = threadIdx.x;
    const int bidx = blockIdx.x;           // 512 blocks
    const int b      = bidx & 31;          // batch; %8 pins batch to one XCD L2
    const int i_base = (bidx >> 5) << 3;   // 8 rows per block
    const int wv     = tid >> 6;           // 0..1
    const int lane   = tid & 63;
    const int rr     = lane >> 4;          // 0..3 row within wave
    const int i      = i_base + (wv << 2) + rr;
    const int j0     = (lane & 15) << 3;   // 8 cols per lane

    __shared__ int   mbuf[TT];             // masks (init only)
    __shared__ float Cbuf[TT];             // C[t] = m_t ? eta*invA_t : 0
    __shared__ float Sbuf[TT];             // S[t] = A_{t-1} (group-local)
    __shared__ float Rbuf[TT / 16];        // R[g] = A_15 (group rescale)
    __shared__ float ybuf[YB][8];          // raw dots, scaled by S at flush

    const float alpha = alpha_p[0];
    const float eta   = eta_p[0];
    const float rcp_a = 1.0f / alpha;

    const float* xb = x + (size_t)b * TT * NN;
    const int*   mb = mask + b * TT;
    float* yout = out + (size_t)BB * NN * NN + (size_t)b * TT * NN;

    // ---- init: masks -> LDS, then per-16-step-group decay tables ----
    {
        int4*       mv = (int4*)mbuf;
        const int4* mg = (const int4*)mb;
        mv[tid]       = mg[tid];
        mv[tid + 128] = mg[tid + 128];
    }
    __syncthreads();
    if (tid < 64) {                        // thread g builds group g (groups independent: V rescaled every 16)
        float e_prev = eta;                // e = eta * invA (invA = prod 1/a), resets per group
        float e      = eta;
#pragma unroll
        for (int k = 0; k < 16; ++k) {
            const int m = mbuf[tid * 16 + k];
            e = m ? e * rcp_a : e;
            Cbuf[tid * 16 + k] = m ? e : 0.0f;
            Sbuf[tid * 16 + k] = eta / e_prev;   // A_{k-1}; full-precision div (init only)
            e_prev = e;
        }
        Rbuf[tid] = eta / e;               // A_15 for the end-of-group V rescale
    }
    __syncthreads();

    const float* wrow = w_init + ((size_t)b * NN + i) * NN + j0;
    float4 v0 = *reinterpret_cast<const float4*>(wrow);
    float4 v1 = *reinterpret_cast<const float4*>(wrow + 4);

    // deep register pipeline: two 8-step buffers, prefetch distance 8-16 steps
    float4 Xc0[8], Xc1[8], Xn0[8], Xn1[8];
    float  xic[8], xin[8];
    float  Cc[16];
    float  p[16];
    float  Rg;

#define LOADG(X0, X1, XI, tbase)                                              \
  {                                                                           \
    const float* gp = xb + (size_t)(tbase) * NN;                              \
    _Pragma("unroll")                                                         \
    for (int k = 0; k < 8; ++k) {                                             \
      X0[k] = *reinterpret_cast<const float4*>(gp + k * NN + j0);             \
      X1[k] = *reinterpret_cast<const float4*>(gp + k * NN + j0 + 4);         \
      XI[k] = gp[k * NN + i];                                                 \
    }                                                                         \
  }

// Cbuf reads are wave-uniform addresses -> LDS broadcast, conflict-free.
#define LOADC(tbase)                                                          \
  {                                                                           \
    _Pragma("unroll")                                                         \
    for (int q = 0; q < 4; ++q)                                               \
      *reinterpret_cast<float4*>(&Cc[q * 4]) =                                \
          *reinterpret_cast<const float4*>(&Cbuf[(tbase) + q * 4]);           \
  }

// dot (reads V pre-update) + 1-FMA/elem factored update. ci = C[t]*x_i.
#define COMPG(X0, X1, XI, cbase, pbase)                                       \
  {                                                                           \
    _Pragma("unroll")                                                         \
    for (int k = 0; k < 8; ++k) {                                             \
      const float ci = Cc[(cbase) + k] * XI[k];                               \
      float d = v0.x * X0[k].x;                                               \
      d = fmaf(v0.y, X0[k].y, d);                                             \
      d = fmaf(v0.z, X0[k].z, d);                                             \
      d = fmaf(v0.w, X0[k].w, d);                                             \
      d = fmaf(v1.x, X1[k].x, d);                                             \
      d = fmaf(v1.y, X1[k].y, d);                                             \
      d = fmaf(v1.z, X1[k].z, d);                                             \
      d = fmaf(v1.w, X1[k].w, d);                                             \
      p[(pbase) + k] = d;                                                     \
      v0.x = fmaf(ci, X0[k].x, v0.x);                                         \
      v0.y = fmaf(ci, X0[k].y, v0.y);                                         \
      v0.z = fmaf(ci, X0[k].z, v0.z);                                         \
      v0.w = fmaf(ci, X0[k].w, v0.w);                                         \
      v1.x = fmaf(ci, X1[k].x, v1.x);                                         \
      v1.y = fmaf(ci, X1[k].y, v1.y);                                         \
      v1.z = fmaf(ci, X1[k].z, v1.z);                                         \
      v1.w = fmaf(ci, X1[k].w, v1.w);                                         \
    }                                                                         \
  }

    LOADG(Xc0, Xc1, xic, 0);
    LOADG(Xn0, Xn1, xin, 8);
    LOADC(0);
    Rg = Rbuf[0];

#pragma unroll 1
    for (int t = 0; t < TT; t += 16) {
        COMPG(Xc0, Xc1, xic, 0, 0);
        if (t + 16 < TT) { LOADG(Xc0, Xc1, xic, t + 16); }
        COMPG(Xn0, Xn1, xin, 8, 8);
        if (t + 24 < TT) { LOADG(Xn0, Xn1, xin, t + 24); }

        // end-of-group rescale: V <- A_15 * V  (V becomes W exactly)
        v0.x *= Rg; v0.y *= Rg; v0.z *= Rg; v0.w *= Rg;
        v1.x *= Rg; v1.y *= Rg; v1.z *= Rg; v1.w *= Rg;

        // prefetch next group's tables (LDS broadcast reads)
        if (t + 16 < TT) { LOADC(t + 16); Rg = Rbuf[(t >> 4) + 1]; }

        // 16 independent 16-lane reduces, stage-outer -> full DPP ILP.
#pragma unroll
        for (int k = 0; k < 16; ++k) { ROR_ADD(p[k], 0x121); }
#pragma unroll
        for (int k = 0; k < 16; ++k) { ROR_ADD(p[k], 0x122); }
#pragma unroll
        for (int k = 0; k < 16; ++k) { ROR_ADD(p[k], 0x124); }
#pragma unroll
        for (int k = 0; k < 16; ++k) { ROR_ADD(p[k], 0x128); }

        if ((lane & 15) == 0) {
#pragma unroll
            for (int k = 0; k < 16; ++k)
                ybuf[(t + k) & (YB - 1)][(wv << 2) + rr] = p[k];
        }

        // Flush 256 buffered raw dots, scaled by S[t] (4x per kernel).
        if (((t + 16) & (YB - 1)) == 0) {
            __syncthreads();
            const int t0 = t + 16 - YB;
#pragma unroll
            for (int pass = 0; pass < 16; ++pass) {
                const int idx = (pass << 7) + tid;   // 0..2047
                const int tq  = idx >> 3;            // 0..255
                const int il  = idx & 7;             // row within block
                yout[(size_t)(t0 + tq) * NN + i_base + il] =
                    ybuf[tq][il] * Sbuf[t0 + tq];
            }
            __syncthreads();
        }
    }
#undef LOADG
#undef LOADC
#undef COMPG

    float* wout = out + ((size_t)b * NN + i) * NN + j0;
    *reinterpret_cast<float4*>(wout)     = v0;
    *reinterpret_cast<float4*>(wout + 4) = v1;
}

extern "C" void kernel_launch(void* const* d_in, const int* in_sizes, int n_in,
                              void* d_out, int out_size, void* d_ws, size_t ws_size,
                              hipStream_t stream)
{
    const float* x      = (const float*)d_in[0];
    const float* w_init = (const float*)d_in[1];
    const float* alpha  = (const float*)d_in[2];
    const float* eta    = (const float*)d_in[3];
    const int*   mask   = (const int*)d_in[4];
    float*       out    = (float*)d_out;

    dim3 grid(512), block(128);
    hipLaunchKernelGGL(bdh_seq_kernel, grid, block, 0, stream,
                       x, w_init, alpha, eta, mask, out);
}